// Round 1
// baseline (820.657 us; speedup 1.0000x reference)
//
#include <hip/hip_runtime.h>
#include <math.h>

#define T_LEN 200
#define E_DIM 64
#define H1_DIM 80
#define H2_DIM 40
#define KPAD 68   // 200*68*4 = 54.4 KB, odd-ish stride in dwords -> bank-friendly
#define NEG_PAD_F (-4294967295.0f)

__device__ __forceinline__ float sigmoidf_fast(float x) {
    return 1.0f / (1.0f + __expf(-x));
}

__global__ __launch_bounds__(256, 2)
void din_attn_kernel(const float* __restrict__ q,     // [B,E]
                     const float* __restrict__ keys,  // [B,T,E]
                     const int*   __restrict__ mask,  // [B,1,T] (0/1)
                     const float* __restrict__ W1,    // [4E,H1] row-major
                     const float* __restrict__ b1,    // [H1]
                     const float* __restrict__ W2,    // [H1,H2]
                     const float* __restrict__ b2,    // [H2]
                     const float* __restrict__ W3,    // [H2]
                     const float* __restrict__ b3,    // [1]
                     float*       __restrict__ out)   // [B,1,E]
{
    __shared__ float q_s[E_DIM];
    __shared__ float K_s[T_LEN * KPAD];
    __shared__ float Wq_s[E_DIM * H1_DIM];   // Wq[e][h], h contiguous
    __shared__ float qc_s[H1_DIM];
    __shared__ float ws[256];                // scores, then softmax weights
    __shared__ float red[256];               // reduction scratch
    __shared__ float part[256];              // output partials

    const int b   = blockIdx.x;
    const int tid = threadIdx.x;

    // ---- stage q and keys tile ----
    if (tid < E_DIM) q_s[tid] = q[(size_t)b * E_DIM + tid];
    const float* kb = keys + (size_t)b * T_LEN * E_DIM;
    for (int idx = tid; idx < T_LEN * E_DIM; idx += 256) {
        int t = idx >> 6, e = idx & 63;
        K_s[t * KPAD + e] = kb[idx];
    }
    __syncthreads();

    // ---- per-batch precompute: qc[h] and Wq[e][h] ----
    // att@W1 = q@(W1a+W1c) + k@(W1b-W1c) + (q*k)@W1d
    if (tid < H1_DIM) {
        float s = b1[tid];
        #pragma unroll
        for (int e = 0; e < E_DIM; ++e)
            s += q_s[e] * (W1[e * H1_DIM + tid] + W1[(128 + e) * H1_DIM + tid]);
        qc_s[tid] = s;
    }
    for (int idx = tid; idx < E_DIM * H1_DIM; idx += 256) {
        int e = idx / H1_DIM;
        Wq_s[idx] = W1[64 * H1_DIM + idx] - W1[128 * H1_DIM + idx]
                  + q_s[e] * W1[192 * H1_DIM + idx];
    }
    __syncthreads();

    // ---- per-position MLP scorer (thread t -> position t) ----
    if (tid < T_LEN) {
        float kreg[E_DIM];
        #pragma unroll
        for (int e4 = 0; e4 < E_DIM; e4 += 4) {
            float4 v = *reinterpret_cast<const float4*>(&K_s[tid * KPAD + e4]);
            kreg[e4] = v.x; kreg[e4 + 1] = v.y; kreg[e4 + 2] = v.z; kreg[e4 + 3] = v.w;
        }

        float h2acc[H2_DIM];
        #pragma unroll
        for (int j = 0; j < H2_DIM; ++j) h2acc[j] = 0.0f;

        for (int hg = 0; hg < H1_DIM; hg += 4) {
            float s0 = qc_s[hg], s1 = qc_s[hg + 1], s2 = qc_s[hg + 2], s3 = qc_s[hg + 3];
            #pragma unroll
            for (int e = 0; e < E_DIM; ++e) {
                float4 w = *reinterpret_cast<const float4*>(&Wq_s[e * H1_DIM + hg]);
                s0 = fmaf(kreg[e], w.x, s0);
                s1 = fmaf(kreg[e], w.y, s1);
                s2 = fmaf(kreg[e], w.z, s2);
                s3 = fmaf(kreg[e], w.w, s3);
            }
            float g0 = sigmoidf_fast(s0);
            float g1 = sigmoidf_fast(s1);
            float g2 = sigmoidf_fast(s2);
            float g3 = sigmoidf_fast(s3);
            // fuse layer-2 accumulation (uniform-address global reads of W2)
            #pragma unroll
            for (int j = 0; j < H2_DIM; j += 4) {
                float4 w0 = *reinterpret_cast<const float4*>(&W2[(hg + 0) * H2_DIM + j]);
                float4 w1 = *reinterpret_cast<const float4*>(&W2[(hg + 1) * H2_DIM + j]);
                float4 w2 = *reinterpret_cast<const float4*>(&W2[(hg + 2) * H2_DIM + j]);
                float4 w3 = *reinterpret_cast<const float4*>(&W2[(hg + 3) * H2_DIM + j]);
                h2acc[j + 0] += g0 * w0.x + g1 * w1.x + g2 * w2.x + g3 * w3.x;
                h2acc[j + 1] += g0 * w0.y + g1 * w1.y + g2 * w2.y + g3 * w3.y;
                h2acc[j + 2] += g0 * w0.z + g1 * w1.z + g2 * w2.z + g3 * w3.z;
                h2acc[j + 3] += g0 * w0.w + g1 * w1.w + g2 * w2.w + g3 * w3.w;
            }
        }

        float score = b3[0];
        #pragma unroll
        for (int j = 0; j < H2_DIM; ++j) {
            float h2v = sigmoidf_fast(h2acc[j] + b2[j]);
            score = fmaf(h2v, W3[j], score);
        }

        bool m = mask[(size_t)b * T_LEN + tid] != 0;
        ws[tid] = m ? score : NEG_PAD_F;
    } else {
        ws[tid] = -INFINITY;  // pad positions: exp -> 0
    }
    __syncthreads();

    // ---- masked softmax over T ----
    red[tid] = ws[tid];
    __syncthreads();
    for (int s = 128; s > 0; s >>= 1) {
        if (tid < s) red[tid] = fmaxf(red[tid], red[tid + s]);
        __syncthreads();
    }
    float mx = red[0];
    __syncthreads();
    float w = (tid < T_LEN) ? __expf(ws[tid] - mx) : 0.0f;
    ws[tid] = w;
    red[tid] = w;
    __syncthreads();
    for (int s = 128; s > 0; s >>= 1) {
        if (tid < s) red[tid] += red[tid + s];
        __syncthreads();
    }
    float inv = 1.0f / red[0];

    // ---- weighted sum of keys: out[b][e] = sum_t w_t * K[t][e] / sum ----
    {
        int g = tid >> 6, e = tid & 63;
        float acc = 0.0f;
        int t0 = g * 50;
        for (int t = t0; t < t0 + 50; ++t)
            acc = fmaf(ws[t], K_s[t * KPAD + e], acc);
        part[tid] = acc;
    }
    __syncthreads();
    if (tid < E_DIM) {
        float o = (part[tid] + part[64 + tid] + part[128 + tid] + part[192 + tid]) * inv;
        out[(size_t)b * E_DIM + tid] = o;
    }
}

extern "C" void kernel_launch(void* const* d_in, const int* in_sizes, int n_in,
                              void* d_out, int out_size, void* d_ws, size_t ws_size,
                              hipStream_t stream) {
    const float* q    = (const float*)d_in[0];
    const float* keys = (const float*)d_in[1];
    const int*   mask = (const int*)  d_in[2];
    const float* W1   = (const float*)d_in[3];
    const float* b1   = (const float*)d_in[4];
    const float* W2   = (const float*)d_in[5];
    const float* b2   = (const float*)d_in[6];
    const float* W3   = (const float*)d_in[7];
    const float* b3   = (const float*)d_in[8];
    float* out = (float*)d_out;

    int B = in_sizes[0] / E_DIM;  // 4096
    din_attn_kernel<<<B, 256, 0, stream>>>(q, keys, mask, W1, b1, W2, b2, W3, b3, out);
}

// Round 2
// 781.842 us; speedup vs baseline: 1.0496x; 1.0496x over previous
//
#include <hip/hip_runtime.h>
#include <math.h>

#define T_LEN 200
#define E_DIM 64
#define H1_DIM 80
#define H2_DIM 40
#define KPAD 68
#define NEG_PAD_F (-4294967295.0f)

__device__ __forceinline__ float sigmoidf_fast(float x) {
    // 1/(1+e^-x) via fast exp + hw rcp (approx ~1ulp, fine at 2e-3 tolerance)
    return __builtin_amdgcn_rcpf(1.0f + __expf(-x));
}

// ---------------------------------------------------------------------------
// Kernel A: per-batch fold of q into layer-1 weights.
//   att@W1 = q@(W1a+W1c) + k@(W1b-W1c) + (q*k)@W1d
//   qc[h]    = b1[h] + sum_e q[e]*(W1a+W1c)[e][h]
//   WqT[h][e]= (W1b-W1c)[e][h] + q[e]*W1d[e][h]     (h-major for scalar rows)
// ---------------------------------------------------------------------------
__global__ __launch_bounds__(256)
void din_prep_kernel(const float* __restrict__ q,    // [B,E]
                     const float* __restrict__ W1,   // [4E,H1]
                     const float* __restrict__ b1,   // [H1]
                     float* __restrict__ qc_ws,      // [B,H1]
                     float* __restrict__ wq_ws)      // [B,H1,E]
{
    __shared__ float q_s[E_DIM];
    const int b = blockIdx.x, tid = threadIdx.x;
    if (tid < E_DIM) q_s[tid] = q[(size_t)b * E_DIM + tid];
    __syncthreads();

    for (int idx = tid; idx < H1_DIM * E_DIM; idx += 256) {
        int h = idx >> 6, e = idx & 63;
        float w = W1[(64 + e) * H1_DIM + h] - W1[(128 + e) * H1_DIM + h]
                + q_s[e] * W1[(192 + e) * H1_DIM + h];
        wq_ws[(size_t)b * H1_DIM * E_DIM + idx] = w;
    }
    if (tid < H1_DIM) {
        float s = b1[tid];
        #pragma unroll 4
        for (int e = 0; e < E_DIM; ++e)
            s += q_s[e] * (W1[e * H1_DIM + tid] + W1[(128 + e) * H1_DIM + tid]);
        qc_ws[(size_t)b * H1_DIM + tid] = s;
    }
}

// ---------------------------------------------------------------------------
// Kernel B: scorer + masked softmax + weighted key sum. All weights read via
// uniform addresses from read-only global -> compiler scalarizes to s_load,
// so the VALU stream is nearly pure v_fmac (vector=keys, scalar=weight).
// LDS is ~3KB -> occupancy is VGPR-bound at 4 waves/SIMD (launch_bounds cap).
// ---------------------------------------------------------------------------
__global__ __launch_bounds__(256, 4)
void din_score_kernel(const float* __restrict__ keys,   // [B,T,E]
                      const int*   __restrict__ mask,   // [B,1,T]
                      const float* __restrict__ qc_ws,  // [B,H1]
                      const float* __restrict__ wq_ws,  // [B,H1,E]
                      const float* __restrict__ W2,     // [H1,H2]
                      const float* __restrict__ b2,     // [H2]
                      const float* __restrict__ W3,     // [H2]
                      const float* __restrict__ b3,     // [1]
                      float*       __restrict__ out)    // [B,1,E]
{
    __shared__ float ws[256];
    __shared__ float red[256];
    __shared__ float part[256];

    const int b = blockIdx.x, tid = threadIdx.x;
    const float* kb = keys  + (size_t)b * T_LEN * E_DIM;
    const float* qc = qc_ws + (size_t)b * H1_DIM;
    const float* wq = wq_ws + (size_t)b * H1_DIM * E_DIM;

    if (tid < T_LEN) {
        // keys row into registers (16 x dwordx4; reused 80x by layer-1)
        float kreg[E_DIM];
        #pragma unroll
        for (int e4 = 0; e4 < E_DIM; e4 += 4) {
            float4 v = *reinterpret_cast<const float4*>(&kb[tid * E_DIM + e4]);
            kreg[e4] = v.x; kreg[e4 + 1] = v.y; kreg[e4 + 2] = v.z; kreg[e4 + 3] = v.w;
        }

        float h2acc[H2_DIM];
        #pragma unroll
        for (int j = 0; j < H2_DIM; ++j) h2acc[j] = 0.0f;

        #pragma unroll 1   // keep body in icache; 20 iterations
        for (int hg = 0; hg < H1_DIM; hg += 4) {
            float s0 = qc[hg + 0], s1 = qc[hg + 1], s2 = qc[hg + 2], s3 = qc[hg + 3];
            const float* w0 = wq + (hg + 0) * E_DIM;
            const float* w1 = wq + (hg + 1) * E_DIM;
            const float* w2 = wq + (hg + 2) * E_DIM;
            const float* w3 = wq + (hg + 3) * E_DIM;
            #pragma unroll
            for (int e = 0; e < E_DIM; ++e) {
                float k = kreg[e];
                s0 = fmaf(k, w0[e], s0);
                s1 = fmaf(k, w1[e], s1);
                s2 = fmaf(k, w2[e], s2);
                s3 = fmaf(k, w3[e], s3);
            }
            float g0 = sigmoidf_fast(s0);
            float g1 = sigmoidf_fast(s1);
            float g2 = sigmoidf_fast(s2);
            float g3 = sigmoidf_fast(s3);
            const float* r0 = W2 + (hg + 0) * H2_DIM;
            const float* r1 = W2 + (hg + 1) * H2_DIM;
            const float* r2 = W2 + (hg + 2) * H2_DIM;
            const float* r3 = W2 + (hg + 3) * H2_DIM;
            #pragma unroll
            for (int j = 0; j < H2_DIM; ++j) {
                h2acc[j] = fmaf(g0, r0[j],
                           fmaf(g1, r1[j],
                           fmaf(g2, r2[j],
                           fmaf(g3, r3[j], h2acc[j]))));
            }
        }

        float score = b3[0];
        #pragma unroll
        for (int j = 0; j < H2_DIM; ++j)
            score = fmaf(sigmoidf_fast(h2acc[j] + b2[j]), W3[j], score);

        ws[tid] = (mask[(size_t)b * T_LEN + tid] != 0) ? score : NEG_PAD_F;
    } else {
        ws[tid] = -INFINITY;  // pad lanes: exp -> 0
    }
    __syncthreads();

    // masked softmax over T (block tree reduce)
    red[tid] = ws[tid];
    __syncthreads();
    for (int s = 128; s > 0; s >>= 1) {
        if (tid < s) red[tid] = fmaxf(red[tid], red[tid + s]);
        __syncthreads();
    }
    float mx = red[0];
    __syncthreads();
    float w = (tid < T_LEN) ? __expf(ws[tid] - mx) : 0.0f;
    ws[tid] = w;
    red[tid] = w;
    __syncthreads();
    for (int s = 128; s > 0; s >>= 1) {
        if (tid < s) red[tid] += red[tid + s];
        __syncthreads();
    }
    float inv = 1.0f / red[0];

    // weighted sum of keys straight from global (coalesced: lane = e)
    {
        int g = tid >> 6, e = tid & 63;
        float acc = 0.0f;
        int t0 = g * 50;
        for (int t = t0; t < t0 + 50; ++t)
            acc = fmaf(ws[t], kb[t * E_DIM + e], acc);
        part[tid] = acc;
    }
    __syncthreads();
    if (tid < E_DIM) {
        float o = (part[tid] + part[64 + tid] + part[128 + tid] + part[192 + tid]) * inv;
        out[(size_t)b * E_DIM + tid] = o;
    }
}

// ---------------------------------------------------------------------------
// Fallback (round-0 kernel, validated): used only if ws_size is too small.
// ---------------------------------------------------------------------------
__global__ __launch_bounds__(256, 2)
void din_attn_fallback(const float* __restrict__ q, const float* __restrict__ keys,
                       const int* __restrict__ mask, const float* __restrict__ W1,
                       const float* __restrict__ b1, const float* __restrict__ W2,
                       const float* __restrict__ b2, const float* __restrict__ W3,
                       const float* __restrict__ b3, float* __restrict__ out)
{
    __shared__ float q_s[E_DIM];
    __shared__ float K_s[T_LEN * KPAD];
    __shared__ float Wq_s[E_DIM * H1_DIM];
    __shared__ float qc_s[H1_DIM];
    __shared__ float ws[256];
    __shared__ float red[256];
    __shared__ float part[256];

    const int b = blockIdx.x, tid = threadIdx.x;
    if (tid < E_DIM) q_s[tid] = q[(size_t)b * E_DIM + tid];
    const float* kb = keys + (size_t)b * T_LEN * E_DIM;
    for (int idx = tid; idx < T_LEN * E_DIM; idx += 256) {
        int t = idx >> 6, e = idx & 63;
        K_s[t * KPAD + e] = kb[idx];
    }
    __syncthreads();
    if (tid < H1_DIM) {
        float s = b1[tid];
        for (int e = 0; e < E_DIM; ++e)
            s += q_s[e] * (W1[e * H1_DIM + tid] + W1[(128 + e) * H1_DIM + tid]);
        qc_s[tid] = s;
    }
    for (int idx = tid; idx < E_DIM * H1_DIM; idx += 256) {
        int e = idx / H1_DIM;
        Wq_s[idx] = W1[64 * H1_DIM + idx] - W1[128 * H1_DIM + idx]
                  + q_s[e] * W1[192 * H1_DIM + idx];
    }
    __syncthreads();
    if (tid < T_LEN) {
        float kreg[E_DIM];
        #pragma unroll
        for (int e4 = 0; e4 < E_DIM; e4 += 4) {
            float4 v = *reinterpret_cast<const float4*>(&K_s[tid * KPAD + e4]);
            kreg[e4] = v.x; kreg[e4 + 1] = v.y; kreg[e4 + 2] = v.z; kreg[e4 + 3] = v.w;
        }
        float h2acc[H2_DIM];
        #pragma unroll
        for (int j = 0; j < H2_DIM; ++j) h2acc[j] = 0.0f;
        for (int hg = 0; hg < H1_DIM; hg += 4) {
            float s0 = qc_s[hg], s1 = qc_s[hg + 1], s2 = qc_s[hg + 2], s3 = qc_s[hg + 3];
            #pragma unroll
            for (int e = 0; e < E_DIM; ++e) {
                float4 wv = *reinterpret_cast<const float4*>(&Wq_s[e * H1_DIM + hg]);
                s0 = fmaf(kreg[e], wv.x, s0);
                s1 = fmaf(kreg[e], wv.y, s1);
                s2 = fmaf(kreg[e], wv.z, s2);
                s3 = fmaf(kreg[e], wv.w, s3);
            }
            float g0 = sigmoidf_fast(s0), g1 = sigmoidf_fast(s1);
            float g2 = sigmoidf_fast(s2), g3 = sigmoidf_fast(s3);
            #pragma unroll
            for (int j = 0; j < H2_DIM; j += 4) {
                float4 w0 = *reinterpret_cast<const float4*>(&W2[(hg + 0) * H2_DIM + j]);
                float4 w1 = *reinterpret_cast<const float4*>(&W2[(hg + 1) * H2_DIM + j]);
                float4 w2 = *reinterpret_cast<const float4*>(&W2[(hg + 2) * H2_DIM + j]);
                float4 w3 = *reinterpret_cast<const float4*>(&W2[(hg + 3) * H2_DIM + j]);
                h2acc[j + 0] += g0 * w0.x + g1 * w1.x + g2 * w2.x + g3 * w3.x;
                h2acc[j + 1] += g0 * w0.y + g1 * w1.y + g2 * w2.y + g3 * w3.y;
                h2acc[j + 2] += g0 * w0.z + g1 * w1.z + g2 * w2.z + g3 * w3.z;
                h2acc[j + 3] += g0 * w0.w + g1 * w1.w + g2 * w2.w + g3 * w3.w;
            }
        }
        float score = b3[0];
        #pragma unroll
        for (int j = 0; j < H2_DIM; ++j)
            score = fmaf(sigmoidf_fast(h2acc[j] + b2[j]), W3[j], score);
        ws[tid] = (mask[(size_t)b * T_LEN + tid] != 0) ? score : NEG_PAD_F;
    } else {
        ws[tid] = -INFINITY;
    }
    __syncthreads();
    red[tid] = ws[tid];
    __syncthreads();
    for (int s = 128; s > 0; s >>= 1) {
        if (tid < s) red[tid] = fmaxf(red[tid], red[tid + s]);
        __syncthreads();
    }
    float mx = red[0];
    __syncthreads();
    float w = (tid < T_LEN) ? __expf(ws[tid] - mx) : 0.0f;
    ws[tid] = w;
    red[tid] = w;
    __syncthreads();
    for (int s = 128; s > 0; s >>= 1) {
        if (tid < s) red[tid] += red[tid + s];
        __syncthreads();
    }
    float inv = 1.0f / red[0];
    {
        int g = tid >> 6, e = tid & 63;
        float acc = 0.0f;
        int t0 = g * 50;
        for (int t = t0; t < t0 + 50; ++t)
            acc = fmaf(ws[t], K_s[t * KPAD + e], acc);
        part[tid] = acc;
    }
    __syncthreads();
    if (tid < E_DIM) {
        float o = (part[tid] + part[64 + tid] + part[128 + tid] + part[192 + tid]) * inv;
        out[(size_t)b * E_DIM + tid] = o;
    }
}

extern "C" void kernel_launch(void* const* d_in, const int* in_sizes, int n_in,
                              void* d_out, int out_size, void* d_ws, size_t ws_size,
                              hipStream_t stream) {
    const float* q    = (const float*)d_in[0];
    const float* keys = (const float*)d_in[1];
    const int*   mask = (const int*)  d_in[2];
    const float* W1   = (const float*)d_in[3];
    const float* b1   = (const float*)d_in[4];
    const float* W2   = (const float*)d_in[5];
    const float* b2   = (const float*)d_in[6];
    const float* W3   = (const float*)d_in[7];
    const float* b3   = (const float*)d_in[8];
    float* out = (float*)d_out;

    const int B = in_sizes[0] / E_DIM;  // 4096
    const size_t ws_needed = (size_t)B * (H1_DIM + H1_DIM * E_DIM) * sizeof(float);

    if (ws_size >= ws_needed) {
        float* qc_ws = (float*)d_ws;                       // [B,80]
        float* wq_ws = qc_ws + (size_t)B * H1_DIM;         // [B,80,64]
        din_prep_kernel<<<B, 256, 0, stream>>>(q, W1, b1, qc_ws, wq_ws);
        din_score_kernel<<<B, 256, 0, stream>>>(keys, mask, qc_ws, wq_ws,
                                                W2, b2, W3, b3, out);
    } else {
        din_attn_fallback<<<B, 256, 0, stream>>>(q, keys, mask, W1, b1,
                                                 W2, b2, W3, b3, out);
    }
}

// Round 3
// 562.255 us; speedup vs baseline: 1.4596x; 1.3905x over previous
//
#include <hip/hip_runtime.h>
#include <math.h>

#define T_LEN 200
#define E_DIM 64
#define H1_DIM 80
#define H2_DIM 40
#define KPAD 68
#define NEG_PAD_F (-4294967295.0f)

__device__ __forceinline__ float sigmoidf_fast(float x) {
    // 1/(1+e^-x) via fast exp + hw rcp; ~1ulp, fine at observed 1e-3 absmax
    return __builtin_amdgcn_rcpf(1.0f + __expf(-x));
}

// ---------------------------------------------------------------------------
// Kernel A (one-shot, tiny): fold W1 [4E,H1] into e-major slices in d_ws.
//   att@W1 = q@(W1a+W1c) + k@(W1b-W1c) + (q*k)@W1d
//   Was[e*80+h] = W1a+W1c   (feeds qc)
//   Wk [e*80+h] = W1b-W1c
//   Wp [e*80+h] = W1d
// Consecutive idx -> h fast -> reads of W1[(off+e)*80+h] are coalesced.
// ---------------------------------------------------------------------------
__global__ void w1_fold_kernel(const float* __restrict__ W1,
                               float* __restrict__ Was,
                               float* __restrict__ Wk,
                               float* __restrict__ Wp)
{
    int idx = blockIdx.x * 256 + threadIdx.x;   // idx = e*H1 + h
    if (idx >= E_DIM * H1_DIM) return;
    int e = idx / H1_DIM;
    float a  = W1[(      e) * H1_DIM + (idx - e * H1_DIM)];
    float bk = W1[( 64 + e) * H1_DIM + (idx - e * H1_DIM)];
    float c  = W1[(128 + e) * H1_DIM + (idx - e * H1_DIM)];
    float d  = W1[(192 + e) * H1_DIM + (idx - e * H1_DIM)];
    Was[idx] = a + c;
    Wk[idx]  = bk - c;
    Wp[idx]  = d;
}

// ---------------------------------------------------------------------------
// Kernel B: per-batch block. Builds Wq (q folded into layer-1) in LDS with
// coalesced reads, then scores 200 positions (thread=position, keys row
// register-resident), masked softmax via shfl, weighted key sum.
// ---------------------------------------------------------------------------
__global__ __launch_bounds__(256, 4)
void din_score2(const float* __restrict__ q,     // [B,E]
                const float* __restrict__ keys,  // [B,T,E]
                const int*   __restrict__ mask,  // [B,1,T]
                const float* __restrict__ Was,   // [E,H1] in d_ws
                const float* __restrict__ Wk,    // [E,H1]
                const float* __restrict__ Wp,    // [E,H1]
                const float* __restrict__ b1,    // [H1]
                const float* __restrict__ W2,    // [H1,H2]
                const float* __restrict__ b2,    // [H2]
                const float* __restrict__ W3,    // [H2]
                const float* __restrict__ b3,    // [1]
                float*       __restrict__ out)   // [B,1,E]
{
    __shared__ float q_s[E_DIM];
    __shared__ float Wq_s[E_DIM * H1_DIM];   // [e][h], h contiguous, 20KB
    __shared__ float qc_s[H1_DIM];
    __shared__ float ws_s[256];
    __shared__ float part[256];
    __shared__ float red_s[4];

    const int b = blockIdx.x, tid = threadIdx.x;
    const int lane = tid & 63, wid = tid >> 6;
    const float* kb = keys + (size_t)b * T_LEN * E_DIM;

    if (tid < E_DIM) q_s[tid] = q[(size_t)b * E_DIM + tid];
    __syncthreads();

    // ---- build Wq in LDS: Wq[e][h] = Wk[e][h] + q[e]*Wp[e][h] (coalesced) ----
    #pragma unroll
    for (int i = 0; i < E_DIM * H1_DIM / 256; ++i) {
        int idx = i * 256 + tid;
        int e = idx / H1_DIM;
        Wq_s[idx] = Wk[idx] + q_s[e] * Wp[idx];
    }
    // ---- qc[h] = b1[h] + sum_e q[e]*Was[e][h] (wave-coalesced per e) ----
    if (tid < H1_DIM) {
        float s = b1[tid];
        #pragma unroll 8
        for (int e = 0; e < E_DIM; ++e)
            s = fmaf(q_s[e], Was[e * H1_DIM + tid], s);
        qc_s[tid] = s;
    }
    __syncthreads();

    float score0 = -INFINITY;
    if (tid < T_LEN) {
        // keys row -> registers, ONCE. The asm memory clobber below makes
        // rematerializing these loads illegal, forcing VGPR residency.
        float kreg[E_DIM];
        #pragma unroll
        for (int e4 = 0; e4 < E_DIM; e4 += 4) {
            float4 v = *reinterpret_cast<const float4*>(&kb[tid * E_DIM + e4]);
            kreg[e4] = v.x; kreg[e4 + 1] = v.y; kreg[e4 + 2] = v.z; kreg[e4 + 3] = v.w;
        }
        asm volatile("" ::: "memory");

        float h2acc[H2_DIM];
        #pragma unroll
        for (int j = 0; j < H2_DIM; ++j) h2acc[j] = 0.0f;

        #pragma unroll 2
        for (int hg = 0; hg < H1_DIM; hg += 4) {
            float4 qv = *reinterpret_cast<const float4*>(&qc_s[hg]);
            float s0 = qv.x, s1 = qv.y, s2 = qv.z, s3 = qv.w;
            #pragma unroll
            for (int e = 0; e < E_DIM; ++e) {
                // broadcast ds_read_b128: 4 h-weights for one e
                float4 w = *reinterpret_cast<const float4*>(&Wq_s[e * H1_DIM + hg]);
                float k = kreg[e];
                s0 = fmaf(k, w.x, s0);
                s1 = fmaf(k, w.y, s1);
                s2 = fmaf(k, w.z, s2);
                s3 = fmaf(k, w.w, s3);
            }
            float g0 = sigmoidf_fast(s0);
            float g1 = sigmoidf_fast(s1);
            float g2 = sigmoidf_fast(s2);
            float g3 = sigmoidf_fast(s3);
            // layer-2: W2 rows via uniform-address global -> scalar operands
            const float* r0 = W2 + (hg + 0) * H2_DIM;
            const float* r1 = W2 + (hg + 1) * H2_DIM;
            const float* r2 = W2 + (hg + 2) * H2_DIM;
            const float* r3 = W2 + (hg + 3) * H2_DIM;
            #pragma unroll
            for (int j = 0; j < H2_DIM; ++j) {
                h2acc[j] = fmaf(g0, r0[j],
                           fmaf(g1, r1[j],
                           fmaf(g2, r2[j],
                           fmaf(g3, r3[j], h2acc[j]))));
            }
        }

        float score = b3[0];
        #pragma unroll
        for (int j = 0; j < H2_DIM; ++j)
            score = fmaf(sigmoidf_fast(h2acc[j] + b2[j]), W3[j], score);

        score0 = (mask[(size_t)b * T_LEN + tid] != 0) ? score : NEG_PAD_F;
    }

    // ---- masked softmax over T: wave shfl reduce + tiny LDS combine ----
    float m = score0;
    #pragma unroll
    for (int off = 32; off > 0; off >>= 1)
        m = fmaxf(m, __shfl_xor(m, off, 64));
    if (lane == 0) red_s[wid] = m;
    __syncthreads();
    float mx = fmaxf(fmaxf(red_s[0], red_s[1]), fmaxf(red_s[2], red_s[3]));

    float w = (tid < T_LEN) ? __expf(score0 - mx) : 0.0f;
    ws_s[tid] = w;
    float sm = w;
    #pragma unroll
    for (int off = 32; off > 0; off >>= 1)
        sm += __shfl_xor(sm, off, 64);
    __syncthreads();          // ws_s visible; also separates red_s reuse
    if (lane == 0) red_s[wid] = sm;
    __syncthreads();
    float inv = 1.0f / (red_s[0] + red_s[1] + red_s[2] + red_s[3]);

    // ---- weighted key sum: lane=e coalesced, 4 wave-groups over t ----
    {
        int g = wid, e = lane;
        float acc = 0.0f;
        int t0 = g * 50;
        #pragma unroll 5
        for (int t = t0; t < t0 + 50; ++t)
            acc = fmaf(ws_s[t], kb[t * E_DIM + e], acc);
        part[tid] = acc;
    }
    __syncthreads();
    if (tid < E_DIM) {
        float o = (part[tid] + part[64 + tid] + part[128 + tid] + part[192 + tid]) * inv;
        out[(size_t)b * E_DIM + tid] = o;
    }
}

// ---------------------------------------------------------------------------
// Fallback (round-0 validated single kernel) if ws_size is too small.
// ---------------------------------------------------------------------------
__global__ __launch_bounds__(256, 2)
void din_attn_fallback(const float* __restrict__ q, const float* __restrict__ keys,
                       const int* __restrict__ mask, const float* __restrict__ W1,
                       const float* __restrict__ b1, const float* __restrict__ W2,
                       const float* __restrict__ b2, const float* __restrict__ W3,
                       const float* __restrict__ b3, float* __restrict__ out)
{
    __shared__ float q_s[E_DIM];
    __shared__ float K_s[T_LEN * KPAD];
    __shared__ float Wq_s[E_DIM * H1_DIM];
    __shared__ float qc_s[H1_DIM];
    __shared__ float ws[256];
    __shared__ float red[256];
    __shared__ float part[256];

    const int b = blockIdx.x, tid = threadIdx.x;
    if (tid < E_DIM) q_s[tid] = q[(size_t)b * E_DIM + tid];
    const float* kb = keys + (size_t)b * T_LEN * E_DIM;
    for (int idx = tid; idx < T_LEN * E_DIM; idx += 256) {
        int t = idx >> 6, e = idx & 63;
        K_s[t * KPAD + e] = kb[idx];
    }
    __syncthreads();
    if (tid < H1_DIM) {
        float s = b1[tid];
        for (int e = 0; e < E_DIM; ++e)
            s += q_s[e] * (W1[e * H1_DIM + tid] + W1[(128 + e) * H1_DIM + tid]);
        qc_s[tid] = s;
    }
    for (int idx = tid; idx < E_DIM * H1_DIM; idx += 256) {
        int e = idx / H1_DIM;
        Wq_s[idx] = W1[64 * H1_DIM + idx] - W1[128 * H1_DIM + idx]
                  + q_s[e] * W1[192 * H1_DIM + idx];
    }
    __syncthreads();
    if (tid < T_LEN) {
        float kreg[E_DIM];
        #pragma unroll
        for (int e4 = 0; e4 < E_DIM; e4 += 4) {
            float4 v = *reinterpret_cast<const float4*>(&K_s[tid * KPAD + e4]);
            kreg[e4] = v.x; kreg[e4 + 1] = v.y; kreg[e4 + 2] = v.z; kreg[e4 + 3] = v.w;
        }
        float h2acc[H2_DIM];
        #pragma unroll
        for (int j = 0; j < H2_DIM; ++j) h2acc[j] = 0.0f;
        for (int hg = 0; hg < H1_DIM; hg += 4) {
            float s0 = qc_s[hg], s1 = qc_s[hg + 1], s2 = qc_s[hg + 2], s3 = qc_s[hg + 3];
            #pragma unroll
            for (int e = 0; e < E_DIM; ++e) {
                float4 wv = *reinterpret_cast<const float4*>(&Wq_s[e * H1_DIM + hg]);
                s0 = fmaf(kreg[e], wv.x, s0);
                s1 = fmaf(kreg[e], wv.y, s1);
                s2 = fmaf(kreg[e], wv.z, s2);
                s3 = fmaf(kreg[e], wv.w, s3);
            }
            float g0 = sigmoidf_fast(s0), g1 = sigmoidf_fast(s1);
            float g2 = sigmoidf_fast(s2), g3 = sigmoidf_fast(s3);
            #pragma unroll
            for (int j = 0; j < H2_DIM; j += 4) {
                float4 w0 = *reinterpret_cast<const float4*>(&W2[(hg + 0) * H2_DIM + j]);
                float4 w1 = *reinterpret_cast<const float4*>(&W2[(hg + 1) * H2_DIM + j]);
                float4 w2 = *reinterpret_cast<const float4*>(&W2[(hg + 2) * H2_DIM + j]);
                float4 w3 = *reinterpret_cast<const float4*>(&W2[(hg + 3) * H2_DIM + j]);
                h2acc[j + 0] += g0 * w0.x + g1 * w1.x + g2 * w2.x + g3 * w3.x;
                h2acc[j + 1] += g0 * w0.y + g1 * w1.y + g2 * w2.y + g3 * w3.y;
                h2acc[j + 2] += g0 * w0.z + g1 * w1.z + g2 * w2.z + g3 * w3.z;
                h2acc[j + 3] += g0 * w0.w + g1 * w1.w + g2 * w2.w + g3 * w3.w;
            }
        }
        float score = b3[0];
        #pragma unroll
        for (int j = 0; j < H2_DIM; ++j)
            score = fmaf(sigmoidf_fast(h2acc[j] + b2[j]), W3[j], score);
        ws[tid] = (mask[(size_t)b * T_LEN + tid] != 0) ? score : NEG_PAD_F;
    } else {
        ws[tid] = -INFINITY;
    }
    __syncthreads();
    red[tid] = ws[tid];
    __syncthreads();
    for (int s = 128; s > 0; s >>= 1) {
        if (tid < s) red[tid] = fmaxf(red[tid], red[tid + s]);
        __syncthreads();
    }
    float mx = red[0];
    __syncthreads();
    float w = (tid < T_LEN) ? __expf(ws[tid] - mx) : 0.0f;
    ws[tid] = w;
    red[tid] = w;
    __syncthreads();
    for (int s = 128; s > 0; s >>= 1) {
        if (tid < s) red[tid] += red[tid + s];
        __syncthreads();
    }
    float inv = 1.0f / red[0];
    {
        int g = tid >> 6, e = tid & 63;
        float acc = 0.0f;
        int t0 = g * 50;
        for (int t = t0; t < t0 + 50; ++t)
            acc = fmaf(ws[t], K_s[t * KPAD + e], acc);
        part[tid] = acc;
    }
    __syncthreads();
    if (tid < E_DIM) {
        float o = (part[tid] + part[64 + tid] + part[128 + tid] + part[192 + tid]) * inv;
        out[(size_t)b * E_DIM + tid] = o;
    }
}

extern "C" void kernel_launch(void* const* d_in, const int* in_sizes, int n_in,
                              void* d_out, int out_size, void* d_ws, size_t ws_size,
                              hipStream_t stream) {
    const float* q    = (const float*)d_in[0];
    const float* keys = (const float*)d_in[1];
    const int*   mask = (const int*)  d_in[2];
    const float* W1   = (const float*)d_in[3];
    const float* b1   = (const float*)d_in[4];
    const float* W2   = (const float*)d_in[5];
    const float* b2   = (const float*)d_in[6];
    const float* W3   = (const float*)d_in[7];
    const float* b3   = (const float*)d_in[8];
    float* out = (float*)d_out;

    const int B = in_sizes[0] / E_DIM;  // 4096
    const size_t ws_needed = (size_t)3 * E_DIM * H1_DIM * sizeof(float);  // 61.4 KB

    if (ws_size >= ws_needed) {
        float* Was = (float*)d_ws;                 // [E,H1]
        float* Wk  = Was + E_DIM * H1_DIM;         // [E,H1]
        float* Wp  = Wk  + E_DIM * H1_DIM;         // [E,H1]
        w1_fold_kernel<<<(E_DIM * H1_DIM + 255) / 256, 256, 0, stream>>>(W1, Was, Wk, Wp);
        din_score2<<<B, 256, 0, stream>>>(q, keys, mask, Was, Wk, Wp,
                                          b1, W2, b2, W3, b3, out);
    } else {
        din_attn_fallback<<<B, 256, 0, stream>>>(q, keys, mask, W1, b1,
                                                 W2, b2, W3, b3, out);
    }
}

// Round 5
// 400.193 us; speedup vs baseline: 2.0507x; 1.4050x over previous
//
#include <hip/hip_runtime.h>
#include <math.h>

#define T_LEN 200
#define E_DIM 64
#define H1_DIM 80
#define H2_DIM 40
#define KPAD 68
#define MPAD 208                 // 13 m-tiles of 16
#define KST 72                   // Kf16 / WqT row stride (halfs), 144B = 16B-aligned
#define W2ST 88                  // W2T row stride (halfs), 176B = 16B-aligned
#define NEG_PAD_F (-4294967295.0f)

typedef _Float16 f16x4 __attribute__((ext_vector_type(4)));
typedef _Float16 f16x8 __attribute__((ext_vector_type(8)));
typedef float    f32x4 __attribute__((ext_vector_type(4)));

__device__ __forceinline__ float sigmoidf_fast(float x) {
    return __builtin_amdgcn_rcpf(1.0f + __expf(-x));
}

// ---------------------------------------------------------------------------
// One-shot fold of W1 [4E,H1] (validated round 3):
//   Was = W1a+W1c (feeds qc) ; Wk = W1b-W1c ; Wp = W1d   (all [e*80+h])
// ---------------------------------------------------------------------------
__global__ void w1_fold_kernel(const float* __restrict__ W1,
                               float* __restrict__ Was,
                               float* __restrict__ Wk,
                               float* __restrict__ Wp)
{
    int idx = blockIdx.x * 256 + threadIdx.x;   // idx = e*H1 + h
    if (idx >= E_DIM * H1_DIM) return;
    int e = idx / H1_DIM;
    int h = idx - e * H1_DIM;
    float a  = W1[(      e) * H1_DIM + h];
    float bk = W1[( 64 + e) * H1_DIM + h];
    float c  = W1[(128 + e) * H1_DIM + h];
    float d  = W1[(192 + e) * H1_DIM + h];
    Was[idx] = a + c;
    Wk[idx]  = bk - c;
    Wp[idx]  = d;
}

// ---------------------------------------------------------------------------
// Main kernel: one block per batch. MFMA f16 pipeline, fully transposed so
// layer-1 D' feeds layer-2 B-operand in-register (no shuffles, no h1 in LDS).
//   D'[h][t]  = sum_e WqT[h][e] * k[t][e]           (16x16x32_f16, K=64)
//   D2[h2][t] = sum_h W2T[h2][h] * sig(D'+qc)[h][t] (16x16x16f16, K=80)
//   score[t]  = sum_h2 sig(D2+b2)[h2][t] * W3[h2]   (b3 dropped: softmax-inv)
// ---------------------------------------------------------------------------
__global__ __launch_bounds__(256, 3)
void din_mfma_kernel(const float* __restrict__ q,     // [B,E]
                     const float* __restrict__ keys,  // [B,T,E]
                     const int*   __restrict__ mask,  // [B,1,T]
                     const float* __restrict__ Was,   // [E,H1] d_ws
                     const float* __restrict__ Wk,    // [E,H1]
                     const float* __restrict__ Wp,    // [E,H1]
                     const float* __restrict__ b1,    // [H1]
                     const float* __restrict__ W2,    // [H1,H2]
                     const float* __restrict__ b2,    // [H2]
                     const float* __restrict__ W3,    // [H2]
                     float*       __restrict__ out)   // [B,1,E]
{
    __shared__ _Float16 Kf16_s[MPAD * KST];        // keys f16, [t][e], 29.95KB
    __shared__ _Float16 WqT_s[H1_DIM * KST];       // Wq^T f16, [h][e], 11.5KB
    __shared__ _Float16 W2T_s[48 * W2ST];          // W2^T f16, [h2][h], 8.4KB
    __shared__ float q_s[E_DIM];
    __shared__ float qc_s[H1_DIM];
    __shared__ float b2_s[48];
    __shared__ float w3_s[48];
    __shared__ float scores_s[MPAD];               // scores, then softmax w
    __shared__ float part[256];
    __shared__ float red_s[4];

    const int b    = blockIdx.x;
    const int tid  = threadIdx.x;
    const int lane = tid & 63;
    const int wid  = tid >> 6;
    const float* kb = keys + (size_t)b * T_LEN * E_DIM;

    if (tid < E_DIM) q_s[tid] = q[(size_t)b * E_DIM + tid];
    __syncthreads();

    // ---- stage keys -> f16 LDS (coalesced float4 reads) ----
    for (int i4 = tid; i4 < T_LEN * 16; i4 += 256) {
        int t = i4 >> 4, e4 = (i4 & 15) << 2;
        float4 kv = *reinterpret_cast<const float4*>(&kb[t * E_DIM + e4]);
        f16x4 hv;
        hv[0] = (_Float16)kv.x; hv[1] = (_Float16)kv.y;
        hv[2] = (_Float16)kv.z; hv[3] = (_Float16)kv.w;
        *reinterpret_cast<f16x4*>(&Kf16_s[t * KST + e4]) = hv;
    }
    // zero pad rows 200..207 (full stride incl col pad)
    for (int i = tid; i < (MPAD - T_LEN) * KST / 2; i += 256)
        reinterpret_cast<unsigned*>(&Kf16_s[T_LEN * KST])[i] = 0u;

    // ---- WqT[h][e] = Wk[e][h] + q[e]*Wp[e][h], f16 ----
    for (int idx = tid; idx < E_DIM * H1_DIM; idx += 256) {
        int e = idx / H1_DIM;
        int h = idx - e * H1_DIM;
        float v = Wk[idx] + q_s[e] * Wp[idx];
        WqT_s[h * KST + e] = (_Float16)v;
    }
    // ---- W2T[h2][h] = W2[h][h2], f16; zero rows h2 in [40,48) ----
    for (int idx = tid; idx < H1_DIM * H2_DIM; idx += 256) {
        int h = idx / H2_DIM;
        int h2 = idx - h * H2_DIM;
        W2T_s[h2 * W2ST + h] = (_Float16)W2[idx];
    }
    for (int i = tid; i < 8 * W2ST / 2; i += 256)
        reinterpret_cast<unsigned*>(&W2T_s[40 * W2ST])[i] = 0u;

    // ---- qc[h] = b1[h] + sum_e q[e]*Was[e][h] ----
    if (tid < H1_DIM) {
        float s = b1[tid];
        #pragma unroll 8
        for (int e = 0; e < E_DIM; ++e)
            s = fmaf(q_s[e], Was[e * H1_DIM + tid], s);
        qc_s[tid] = s;
    }
    if (tid < 48) {
        b2_s[tid] = (tid < H2_DIM) ? b2[tid] : 0.0f;
        w3_s[tid] = (tid < H2_DIM) ? W3[tid] : 0.0f;
    }
    __syncthreads();

    // ---- per-wave independent m-tiles (13 tiles / 4 waves) ----
    const int r16 = lane & 15, g4 = lane >> 4;
    for (int mt = wid; mt < MPAD / 16; mt += 4) {
        // B-operand (keys^T): row t = mt*16 + r16, k=e contiguous
        const _Float16* kr = &Kf16_s[(mt * 16 + r16) * KST + g4 * 8];
        f16x8 kb0 = *reinterpret_cast<const f16x8*>(kr);
        f16x8 kb1 = *reinterpret_cast<const f16x8*>(kr + 32);

        // layer-1 per h-tile -> sigmoid -> f16 B-frags for layer-2
        f16x4 bfr[5];
        #pragma unroll
        for (int ht = 0; ht < 5; ++ht) {
            const _Float16* ar = &WqT_s[(ht * 16 + r16) * KST + g4 * 8];
            f16x8 a0 = *reinterpret_cast<const f16x8*>(ar);
            f16x8 a1 = *reinterpret_cast<const f16x8*>(ar + 32);
            f32x4 acc = {0.f, 0.f, 0.f, 0.f};
            acc = __builtin_amdgcn_mfma_f32_16x16x32_f16(a0, kb0, acc, 0, 0, 0);
            acc = __builtin_amdgcn_mfma_f32_16x16x32_f16(a1, kb1, acc, 0, 0, 0);
            f32x4 qcv = *reinterpret_cast<const f32x4*>(&qc_s[ht * 16 + g4 * 4]);
            #pragma unroll
            for (int j = 0; j < 4; ++j)
                bfr[ht][j] = (_Float16)sigmoidf_fast(acc[j] + qcv[j]);
        }

        // layer-2 (K=80 = 5x16) + layer-3 partial
        float partial = 0.0f;
        #pragma unroll
        for (int nt2 = 0; nt2 < 3; ++nt2) {
            f32x4 d2 = {0.f, 0.f, 0.f, 0.f};
            #pragma unroll
            for (int ks = 0; ks < 5; ++ks) {
                f16x4 a2 = *reinterpret_cast<const f16x4*>(
                    &W2T_s[(nt2 * 16 + r16) * W2ST + ks * 16 + g4 * 4]);
                d2 = __builtin_amdgcn_mfma_f32_16x16x16f16(a2, bfr[ks], d2, 0, 0, 0);
            }
            f32x4 b2v = *reinterpret_cast<const f32x4*>(&b2_s[nt2 * 16 + g4 * 4]);
            f32x4 w3v = *reinterpret_cast<const f32x4*>(&w3_s[nt2 * 16 + g4 * 4]);
            #pragma unroll
            for (int j = 0; j < 4; ++j)
                partial = fmaf(sigmoidf_fast(d2[j] + b2v[j]), w3v[j], partial);
        }
        // positions live in lane&15; sum the 4 lane-groups
        partial += __shfl_xor(partial, 16);
        partial += __shfl_xor(partial, 32);
        if (lane < 16) scores_s[mt * 16 + lane] = partial;
    }
    __syncthreads();

    // ---- masked softmax over T ----
    float score0 = -INFINITY;
    if (tid < T_LEN)
        score0 = (mask[(size_t)b * T_LEN + tid] != 0) ? scores_s[tid] : NEG_PAD_F;

    float m = score0;
    #pragma unroll
    for (int off = 32; off > 0; off >>= 1)
        m = fmaxf(m, __shfl_xor(m, off, 64));
    if (lane == 0) red_s[wid] = m;
    __syncthreads();
    float mx = fmaxf(fmaxf(red_s[0], red_s[1]), fmaxf(red_s[2], red_s[3]));

    float w = (tid < T_LEN) ? __expf(score0 - mx) : 0.0f;
    float sm = w;
    #pragma unroll
    for (int off = 32; off > 0; off >>= 1)
        sm += __shfl_xor(sm, off, 64);
    __syncthreads();                 // all scores_s reads done -> safe to reuse
    if (tid < MPAD) scores_s[tid] = w;
    if (lane == 0) red_s[wid] = sm;
    __syncthreads();
    float inv = 1.0f / (red_s[0] + red_s[1] + red_s[2] + red_s[3]);

    // ---- weighted key sum from global (L3-resident second pass) ----
    {
        int e = lane;
        float acc = 0.0f;
        int t0 = wid * 50;
        #pragma unroll 5
        for (int t = t0; t < t0 + 50; ++t)
            acc = fmaf(scores_s[t], kb[t * E_DIM + e], acc);
        part[tid] = acc;
    }
    __syncthreads();
    if (tid < E_DIM) {
        float o = (part[tid] + part[64 + tid] + part[128 + tid] + part[192 + tid]) * inv;
        out[(size_t)b * E_DIM + tid] = o;
    }
}

// ---------------------------------------------------------------------------
// Fallback (round-0 validated, self-contained) if ws_size too small.
// ---------------------------------------------------------------------------
__global__ __launch_bounds__(256, 2)
void din_attn_fallback(const float* __restrict__ q, const float* __restrict__ keys,
                       const int* __restrict__ mask, const float* __restrict__ W1,
                       const float* __restrict__ b1, const float* __restrict__ W2,
                       const float* __restrict__ b2, const float* __restrict__ W3,
                       const float* __restrict__ b3, float* __restrict__ out)
{
    __shared__ float q_s[E_DIM];
    __shared__ float K_s[T_LEN * KPAD];
    __shared__ float Wq_s[E_DIM * H1_DIM];
    __shared__ float qc_s[H1_DIM];
    __shared__ float ws[256];
    __shared__ float red[256];
    __shared__ float part[256];

    const int b = blockIdx.x, tid = threadIdx.x;
    if (tid < E_DIM) q_s[tid] = q[(size_t)b * E_DIM + tid];
    const float* kb = keys + (size_t)b * T_LEN * E_DIM;
    for (int idx = tid; idx < T_LEN * E_DIM; idx += 256) {
        int t = idx >> 6, e = idx & 63;
        K_s[t * KPAD + e] = kb[idx];
    }
    __syncthreads();
    if (tid < H1_DIM) {
        float s = b1[tid];
        for (int e = 0; e < E_DIM; ++e)
            s += q_s[e] * (W1[e * H1_DIM + tid] + W1[(128 + e) * H1_DIM + tid]);
        qc_s[tid] = s;
    }
    for (int idx = tid; idx < E_DIM * H1_DIM; idx += 256) {
        int e = idx / H1_DIM;
        Wq_s[idx] = W1[64 * H1_DIM + idx] - W1[128 * H1_DIM + idx]
                  + q_s[e] * W1[192 * H1_DIM + idx];
    }
    __syncthreads();
    if (tid < T_LEN) {
        float kreg[E_DIM];
        #pragma unroll
        for (int e4 = 0; e4 < E_DIM; e4 += 4) {
            float4 v = *reinterpret_cast<const float4*>(&K_s[tid * KPAD + e4]);
            kreg[e4] = v.x; kreg[e4 + 1] = v.y; kreg[e4 + 2] = v.z; kreg[e4 + 3] = v.w;
        }
        float h2acc[H2_DIM];
        #pragma unroll
        for (int j = 0; j < H2_DIM; ++j) h2acc[j] = 0.0f;
        for (int hg = 0; hg < H1_DIM; hg += 4) {
            float s0 = qc_s[hg], s1 = qc_s[hg + 1], s2 = qc_s[hg + 2], s3 = qc_s[hg + 3];
            #pragma unroll
            for (int e = 0; e < E_DIM; ++e) {
                float4 wv = *reinterpret_cast<const float4*>(&Wq_s[e * H1_DIM + hg]);
                s0 = fmaf(kreg[e], wv.x, s0);
                s1 = fmaf(kreg[e], wv.y, s1);
                s2 = fmaf(kreg[e], wv.z, s2);
                s3 = fmaf(kreg[e], wv.w, s3);
            }
            float g0 = sigmoidf_fast(s0), g1 = sigmoidf_fast(s1);
            float g2 = sigmoidf_fast(s2), g3 = sigmoidf_fast(s3);
            #pragma unroll
            for (int j = 0; j < H2_DIM; j += 4) {
                float4 w0 = *reinterpret_cast<const float4*>(&W2[(hg + 0) * H2_DIM + j]);
                float4 w1 = *reinterpret_cast<const float4*>(&W2[(hg + 1) * H2_DIM + j]);
                float4 w2 = *reinterpret_cast<const float4*>(&W2[(hg + 2) * H2_DIM + j]);
                float4 w3 = *reinterpret_cast<const float4*>(&W2[(hg + 3) * H2_DIM + j]);
                h2acc[j + 0] += g0 * w0.x + g1 * w1.x + g2 * w2.x + g3 * w3.x;
                h2acc[j + 1] += g0 * w0.y + g1 * w1.y + g2 * w2.y + g3 * w3.y;
                h2acc[j + 2] += g0 * w0.z + g1 * w1.z + g2 * w2.z + g3 * w3.z;
                h2acc[j + 3] += g0 * w0.w + g1 * w1.w + g2 * w2.w + g3 * w3.w;
            }
        }
        float score = b3[0];
        #pragma unroll
        for (int j = 0; j < H2_DIM; ++j)
            score = fmaf(sigmoidf_fast(h2acc[j] + b2[j]), W3[j], score);
        ws[tid] = (mask[(size_t)b * T_LEN + tid] != 0) ? score : NEG_PAD_F;
    } else {
        ws[tid] = -INFINITY;
    }
    __syncthreads();
    red[tid] = ws[tid];
    __syncthreads();
    for (int s = 128; s > 0; s >>= 1) {
        if (tid < s) red[tid] = fmaxf(red[tid], red[tid + s]);
        __syncthreads();
    }
    float mx = red[0];
    __syncthreads();
    float w = (tid < T_LEN) ? __expf(ws[tid] - mx) : 0.0f;
    ws[tid] = w;
    red[tid] = w;
    __syncthreads();
    for (int s = 128; s > 0; s >>= 1) {
        if (tid < s) red[tid] += red[tid + s];
        __syncthreads();
    }
    float inv = 1.0f / red[0];
    {
        int g = tid >> 6, e = tid & 63;
        float acc = 0.0f;
        int t0 = g * 50;
        for (int t = t0; t < t0 + 50; ++t)
            acc = fmaf(ws[t], K_s[t * KPAD + e], acc);
        part[tid] = acc;
    }
    __syncthreads();
    if (tid < E_DIM) {
        float o = (part[tid] + part[64 + tid] + part[128 + tid] + part[192 + tid]) * inv;
        out[(size_t)b * E_DIM + tid] = o;
    }
}

extern "C" void kernel_launch(void* const* d_in, const int* in_sizes, int n_in,
                              void* d_out, int out_size, void* d_ws, size_t ws_size,
                              hipStream_t stream) {
    const float* q    = (const float*)d_in[0];
    const float* keys = (const float*)d_in[1];
    const int*   mask = (const int*)  d_in[2];
    const float* W1   = (const float*)d_in[3];
    const float* b1   = (const float*)d_in[4];
    const float* W2   = (const float*)d_in[5];
    const float* b2   = (const float*)d_in[6];
    const float* W3   = (const float*)d_in[7];
    const float* b3   = (const float*)d_in[8];
    float* out = (float*)d_out;

    const int B = in_sizes[0] / E_DIM;  // 4096
    const size_t ws_needed = (size_t)3 * E_DIM * H1_DIM * sizeof(float);  // 61.4 KB

    if (ws_size >= ws_needed) {
        float* Was = (float*)d_ws;
        float* Wk  = Was + E_DIM * H1_DIM;
        float* Wp  = Wk  + E_DIM * H1_DIM;
        w1_fold_kernel<<<(E_DIM * H1_DIM + 255) / 256, 256, 0, stream>>>(W1, Was, Wk, Wp);
        din_mfma_kernel<<<B, 256, 0, stream>>>(q, keys, mask, Was, Wk, Wp,
                                               b1, W2, b2, W3, out);
    } else {
        din_attn_fallback<<<B, 256, 0, stream>>>(q, keys, mask, W1, b1,
                                                 W2, b2, W3, b3, out);
    }
}